// Round 1
// baseline (979.725 us; speedup 1.0000x reference)
//
#include <hip/hip_runtime.h>

#define DDIM 256          // feature dim
#define EPS  1e-12f

// Kernel 1: zero the output accumulator + compute 1/max(||g||,eps) per row
// for both g1_target and g2_target. One wave (64 lanes) per row; each lane
// loads a float4 (64*16B = 1KB = full row), tree-reduce sum of squares.
__global__ void __launch_bounds__(256) invnorm_kernel(
    const float* __restrict__ g1, const float* __restrict__ g2,
    float* __restrict__ inv1, float* __restrict__ inv2,
    float* __restrict__ out, int G) {
  if (blockIdx.x == 0 && threadIdx.x == 0) out[0] = 0.0f;
  int lane = threadIdx.x & 63;
  int wave = blockIdx.x * (blockDim.x >> 6) + (threadIdx.x >> 6);
  if (wave >= 2 * G) return;
  const float* src;
  float* dst;
  int row;
  if (wave < G) { src = g1; dst = inv1; row = wave; }
  else          { src = g2; dst = inv2; row = wave - G; }
  float4 v = ((const float4*)(src + (size_t)row * DDIM))[lane];
  float ss = fmaf(v.x, v.x, fmaf(v.y, v.y, fmaf(v.z, v.z, v.w * v.w)));
#pragma unroll
  for (int off = 32; off; off >>= 1) ss += __shfl_down(ss, off);
  if (lane == 0) dst[row] = 1.0f / fmaxf(sqrtf(ss), EPS);
}

// Kernel 2: loss = (1/G) * sum_i [ dot(h1_i, g2_{b_i}) * inv|h1_i| * inv|g2_{b_i}|
//                                + dot(h2_i, g1_{b_i}) * inv|h2_i| * inv|g1_{b_i}| ]
// One wave per row; waves own contiguous row chunks (batch is sorted -> the
// g row a wave needs stays cached across its ~62 iterations).
__global__ void __launch_bounds__(256) loss_kernel(
    const float* __restrict__ h1, const float* __restrict__ h2,
    const float* __restrict__ g1, const float* __restrict__ g2,
    const float* __restrict__ inv1, const float* __restrict__ inv2,
    const int* __restrict__ batch, float* __restrict__ out,
    int N, int G, int chunk) {
  int lane = threadIdx.x & 63;
  int wib  = threadIdx.x >> 6;
  int wave = blockIdx.x * (blockDim.x >> 6) + wib;
  int start = wave * chunk;
  int end   = start + chunk;
  if (end > N) end = N;
  float acc = 0.0f;
  for (int i = start; i < end; ++i) {
    int g = batch[i];
    const float4* a4 = (const float4*)(h1 + (size_t)i * DDIM) + lane;
    const float4* c4 = (const float4*)(h2 + (size_t)i * DDIM) + lane;
    const float4* b4 = (const float4*)(g2 + (size_t)g * DDIM) + lane;
    const float4* d4 = (const float4*)(g1 + (size_t)g * DDIM) + lane;
    float4 a = *a4;
    float4 b = *b4;
    float4 c = *c4;
    float4 d = *d4;
    float ss1 = fmaf(a.x, a.x, fmaf(a.y, a.y, fmaf(a.z, a.z, a.w * a.w)));
    float d1  = fmaf(a.x, b.x, fmaf(a.y, b.y, fmaf(a.z, b.z, a.w * b.w)));
    float ss2 = fmaf(c.x, c.x, fmaf(c.y, c.y, fmaf(c.z, c.z, c.w * c.w)));
    float d2  = fmaf(c.x, d.x, fmaf(c.y, d.y, fmaf(c.z, d.z, c.w * d.w)));
#pragma unroll
    for (int off = 32; off; off >>= 1) {
      ss1 += __shfl_down(ss1, off);
      d1  += __shfl_down(d1,  off);
      ss2 += __shfl_down(ss2, off);
      d2  += __shfl_down(d2,  off);
    }
    if (lane == 0) {
      acc += d1 * inv2[g] / fmaxf(sqrtf(ss1), EPS)
           + d2 * inv1[g] / fmaxf(sqrtf(ss2), EPS);
    }
  }
  __shared__ float sred[4];
  if (lane == 0) sred[wib] = acc;
  __syncthreads();
  if (threadIdx.x == 0) {
    float t = sred[0] + sred[1] + sred[2] + sred[3];
    atomicAdd(out, t / (float)G);
  }
}

extern "C" void kernel_launch(void* const* d_in, const int* in_sizes, int n_in,
                              void* d_out, int out_size, void* d_ws, size_t ws_size,
                              hipStream_t stream) {
  const float* h1 = (const float*)d_in[0];
  const float* h2 = (const float*)d_in[1];
  const float* g1 = (const float*)d_in[2];
  const float* g2 = (const float*)d_in[3];
  const int* batch = (const int*)d_in[4];
  float* out = (float*)d_out;

  int N = in_sizes[0] / DDIM;   // 500000
  int G = in_sizes[2] / DDIM;   // 8192

  float* inv1 = (float*)d_ws;
  float* inv2 = inv1 + G;

  // Kernel 1: 2*G waves, 4 waves/block
  int waves1 = 2 * G;
  int blocks1 = (waves1 + 3) / 4;
  invnorm_kernel<<<blocks1, 256, 0, stream>>>(g1, g2, inv1, inv2, out, G);

  // Kernel 2: 2048 blocks * 4 waves = 8192 waves, contiguous chunks
  int blocks2 = 2048;
  int numWaves = blocks2 * 4;
  int chunk = (N + numWaves - 1) / numWaves;
  loss_kernel<<<blocks2, 256, 0, stream>>>(h1, h2, g1, g2, inv1, inv2,
                                           batch, out, N, G, chunk);
}

// Round 2
// 912.988 us; speedup vs baseline: 1.0731x; 1.0731x over previous
//
#include <hip/hip_runtime.h>

#define DDIM 256          // feature dim
#define EPS  1e-12f
#define NBLK 2048
#define WPB  4            // waves per block

typedef float v4 __attribute__((ext_vector_type(4)));

__device__ __forceinline__ float dot4(v4 a, v4 b) {
  return fmaf(a.x, b.x, fmaf(a.y, b.y, fmaf(a.z, b.z, a.w * b.w)));
}

// loss = (1/G) * sum_i [ dot(h1_i,g2_b)/(|h1_i||g2_b|) + dot(h2_i,g1_b)/(|h2_i||g1_b|) ]
// One wave per contiguous 62-row chunk; batch sorted -> g rows held in VGPRs
// across iterations, inv-norms recomputed only on (rare, wave-uniform) g change.
__global__ void __launch_bounds__(256, 8) loss_kernel(
    const float* __restrict__ h1, const float* __restrict__ h2,
    const float* __restrict__ g1, const float* __restrict__ g2,
    const int* __restrict__ batch, float* __restrict__ partials,
    int N, int chunk) {
  int lane = threadIdx.x & 63;
  int wib  = threadIdx.x >> 6;
  int wave = blockIdx.x * WPB + wib;
  int start = __builtin_amdgcn_readfirstlane(wave * chunk);
  int end = start + chunk;
  if (end > N) end = N;

  float acc = 0.0f;
  int gprev = -1;
  float inv1c = 0.0f, inv2c = 0.0f;
  v4 b4 = (v4)0.0f, d4 = (v4)0.0f;   // register-cached g2/g1 row fragments

  int i = start;
  v4 a4 = (v4)0.0f, c4 = (v4)0.0f;
  if (i < end) {
    a4 = __builtin_nontemporal_load((const v4*)(h1 + (size_t)i * DDIM) + lane);
    c4 = __builtin_nontemporal_load((const v4*)(h2 + (size_t)i * DDIM) + lane);
  }

  for (; i < end; ++i) {
    v4 a = a4, c = c4;
    int inext = i + 1;
    if (inext < end) {  // prefetch next rows across the reduction chain
      a4 = __builtin_nontemporal_load((const v4*)(h1 + (size_t)inext * DDIM) + lane);
      c4 = __builtin_nontemporal_load((const v4*)(h2 + (size_t)inext * DDIM) + lane);
    }
    int g = batch[i];                 // scalar (uniform) load
    if (g != gprev) {                 // wave-uniform branch, ~2x per chunk
      gprev = g;
      b4 = *((const v4*)(g2 + (size_t)g * DDIM) + lane);
      d4 = *((const v4*)(g1 + (size_t)g * DDIM) + lane);
      float sb = dot4(b4, b4), sd = dot4(d4, d4);
#pragma unroll
      for (int off = 32; off; off >>= 1) {
        sb += __shfl_xor(sb, off);
        sd += __shfl_xor(sd, off);
      }
      inv2c = 1.0f / fmaxf(sqrtf(sb), EPS);
      inv1c = 1.0f / fmaxf(sqrtf(sd), EPS);
    }
    // per-lane partials
    float ss1 = dot4(a, a), d1 = dot4(a, b4);
    float ss2 = dot4(c, c), d2 = dot4(c, d4);
    // interleaved 4-value reduction: 11 shuffles instead of 24.
    float A = ss1 + __shfl_xor(ss1, 32);
    float B = d1  + __shfl_xor(d1,  32);
    float C = ss2 + __shfl_xor(ss2, 32);
    float D = d2  + __shfl_xor(d2,  32);
    float e1 = (lane & 32) ? B : A;
    float e2 = (lane & 32) ? D : C;
    e1 += __shfl_xor(e1, 16);
    e2 += __shfl_xor(e2, 16);
    float f = (lane & 16) ? e2 : e1;
    f += __shfl_xor(f, 8);
    f += __shfl_xor(f, 4);
    f += __shfl_xor(f, 2);
    f += __shfl_xor(f, 1);
    // lanes 0-15: f=tot(ss1); 16-31: f=tot(ss2); 32-47: tot(d1); 48-63: tot(d2)
    float t = __shfl_xor(f, 32);      // lane0: tot(d1), lane16: tot(d2)
    float invg = (lane & 16) ? inv1c : inv2c;
    float contrib = t * invg / fmaxf(sqrtf(f), EPS);
    if (lane == 0 || lane == 16) acc += contrib;
  }

  acc += __shfl_down(acc, 16);        // lane0 += lane16's accumulator
  __shared__ float sred[WPB];
  if (lane == 0) sred[wib] = acc;
  __syncthreads();
  if (threadIdx.x == 0)
    partials[blockIdx.x] = sred[0] + sred[1] + sred[2] + sred[3];
}

__global__ void __launch_bounds__(256) finalize_kernel(
    const float* __restrict__ partials, float* __restrict__ out, float invG) {
  int t = threadIdx.x;
  float s = 0.0f;
#pragma unroll
  for (int k = 0; k < NBLK / 256; ++k) s += partials[t + 256 * k];
#pragma unroll
  for (int off = 32; off; off >>= 1) s += __shfl_xor(s, off);
  __shared__ float sr[4];
  int lane = t & 63, wib = t >> 6;
  if (lane == 0) sr[wib] = s;
  __syncthreads();
  if (t == 0) out[0] = (sr[0] + sr[1] + sr[2] + sr[3]) * invG;
}

extern "C" void kernel_launch(void* const* d_in, const int* in_sizes, int n_in,
                              void* d_out, int out_size, void* d_ws, size_t ws_size,
                              hipStream_t stream) {
  const float* h1 = (const float*)d_in[0];
  const float* h2 = (const float*)d_in[1];
  const float* g1 = (const float*)d_in[2];
  const float* g2 = (const float*)d_in[3];
  const int* batch = (const int*)d_in[4];
  float* out = (float*)d_out;

  int N = in_sizes[0] / DDIM;   // 500000
  int G = in_sizes[2] / DDIM;   // 8192

  float* partials = (float*)d_ws;   // NBLK floats; every block writes its slot

  int numWaves = NBLK * WPB;
  int chunk = (N + numWaves - 1) / numWaves;
  loss_kernel<<<NBLK, 256, 0, stream>>>(h1, h2, g1, g2, batch, partials, N, chunk);
  finalize_kernel<<<1, 256, 0, stream>>>(partials, out, 1.0f / (float)G);
}